// Round 12
// baseline (465.922 us; speedup 1.0000x reference)
//
#include <hip/hip_runtime.h>
#include <hip/hip_bf16.h>
#include <stdint.h>

typedef __bf16 bf16_t;
typedef __bf16 bf16x8 __attribute__((ext_vector_type(8)));
typedef float f32x4 __attribute__((ext_vector_type(4)));

#define M_ROWS 8192
#define N_COLS 4096
#define K_DIM  4096
#define KEXT   64
#define BM 256
#define BN 256
#define BK 64
#define NT 65   // 64 main K-tiles + 1 LoRA extension tile

// ws layout
#define XBF_BYTES (67108864ull)   // 8192*4096*2
#define WBF_BYTES (33554432ull)   // 4096*4096*2
#define LOW_BYTES (1048576ull)    // 8192*64*2
#define LBT_BYTES (2097152ull)    // 4*4096*64*2
#define LAT_BYTES (524288ull)     // 4*16*4096*2

__device__ __forceinline__ void gload16(const void* g, void* l) {
    __builtin_amdgcn_global_load_lds(
        (const __attribute__((address_space(1))) unsigned int*)g,
        (__attribute__((address_space(3))) unsigned int*)l, 16, 0, 0);
}

// ---------------------------------------------------------------------------
// Streaming prep (all coalesced):
//   [0..511]     Xbf = bf16(x)
//   [512..1535]  Wbf = bf16(weight)
//   [1536..1599] lBt[b][n][r] = 2*lora_B[b][r][n] (+zero pad r=16..63)
//   [1600..1663] lAT[b][c][k] = bf16(lora_A[b][k][c])
__global__ __launch_bounds__(256) void prep_kernel(
    const float* __restrict__ x, const float* __restrict__ lA,
    const float* __restrict__ lB, const float* __restrict__ weight,
    bf16_t* __restrict__ Xbf, bf16_t* __restrict__ Wbf,
    bf16_t* __restrict__ lBt, bf16_t* __restrict__ lAT)
{
    const int blk = blockIdx.x;
    const int tid = threadIdx.x;

    if (blk < 512) {
        const long long i0 = (long long)blk * 256 + tid;
        #pragma unroll 1
        for (int it = 0; it < 32; ++it) {
            const long long i = i0 + (long long)it * 131072;
            const f32x4* s = (const f32x4*)(x + i * 8);
            const f32x4 a = s[0], b = s[1];
            bf16x8 v;
            v[0]=(bf16_t)a[0]; v[1]=(bf16_t)a[1]; v[2]=(bf16_t)a[2]; v[3]=(bf16_t)a[3];
            v[4]=(bf16_t)b[0]; v[5]=(bf16_t)b[1]; v[6]=(bf16_t)b[2]; v[7]=(bf16_t)b[3];
            *(bf16x8*)(Xbf + i * 8) = v;
        }
    } else if (blk < 1536) {
        const long long i0 = (long long)(blk - 512) * 256 + tid;
        #pragma unroll 1
        for (int it = 0; it < 8; ++it) {
            const long long i = i0 + (long long)it * 262144;
            const f32x4* s = (const f32x4*)(weight + i * 8);
            const f32x4 a = s[0], b = s[1];
            bf16x8 v;
            v[0]=(bf16_t)a[0]; v[1]=(bf16_t)a[1]; v[2]=(bf16_t)a[2]; v[3]=(bf16_t)a[3];
            v[4]=(bf16_t)b[0]; v[5]=(bf16_t)b[1]; v[6]=(bf16_t)b[2]; v[7]=(bf16_t)b[3];
            *(bf16x8*)(Wbf + i * 8) = v;
        }
    } else if (blk < 1600) {
        const int idx = (blk - 1536) * 256 + tid;   // 0..16383
        const int b = idx >> 12, n = idx & 4095;
        const float* src = lB + (size_t)b * (16 * N_COLS) + n;
        bf16_t* dst = lBt + ((size_t)b * N_COLS + n) * KEXT;
        bf16x8 v0, v1, z;
        #pragma unroll
        for (int r = 0; r < 8; ++r) {
            v0[r] = (bf16_t)(2.0f * src[(size_t)r * N_COLS]);
            v1[r] = (bf16_t)(2.0f * src[(size_t)(8 + r) * N_COLS]);
            z[r]  = (bf16_t)0.0f;
        }
        *(bf16x8*)(dst)     = v0;
        *(bf16x8*)(dst + 8) = v1;
        #pragma unroll
        for (int c = 16; c < 64; c += 8)
            *(bf16x8*)(dst + c) = z;
    } else {
        const int q = blk - 1600;              // 0..63
        const int b = q >> 4, c = q & 15;
        const float* src = lA + (size_t)b * (K_DIM * 16) + c;
        bf16_t* dst = lAT + ((size_t)b * 16 + c) * K_DIM + tid * 16;
        bf16x8 v0, v1;
        #pragma unroll
        for (int j = 0; j < 8; ++j) {
            v0[j] = (bf16_t)src[(size_t)(tid * 16 + j) * 16];
            v1[j] = (bf16_t)src[(size_t)(tid * 16 + 8 + j) * 16];
        }
        *(bf16x8*)(dst)     = v0;
        *(bf16x8*)(dst + 8) = v1;
    }
}

// ---------------------------------------------------------------------------
// low = Xbf @ lora_A via MFMA. 256 blocks x 32 rows; 4 waves =
// (rowg 0..1 -> 16 rows) x (khalf 0..1 -> K half). 2 interleaved acc chains.
__global__ __launch_bounds__(256) void lowg_kernel(
    const bf16_t* __restrict__ Xbf, const bf16_t* __restrict__ lAT,
    bf16_t* __restrict__ lowbf)
{
    __shared__ f32x4 lsum[128];
    const int tid  = threadIdx.x;
    const int w    = tid >> 6;
    const int lane = tid & 63;
    const int rowg = w >> 1, khalf = w & 1;
    const int m0   = blockIdx.x * 32;
    const int batch = m0 >> 11;
    const int r16  = lane & 15;
    const int kg   = lane >> 4;

    const bf16_t* aB = Xbf + (size_t)(m0 + rowg * 16 + r16) * K_DIM + khalf * 2048 + kg * 8;
    const bf16_t* bB = lAT + ((size_t)batch * 16 + r16) * K_DIM + khalf * 2048 + kg * 8;

    f32x4 acc0 = (f32x4)0.0f, acc1 = (f32x4)0.0f;
    #pragma unroll 4
    for (int ks = 0; ks < 32; ++ks) {
        acc0 = __builtin_amdgcn_mfma_f32_16x16x32_bf16(
            *(const bf16x8*)(aB + ks * 64), *(const bf16x8*)(bB + ks * 64), acc0, 0, 0, 0);
        acc1 = __builtin_amdgcn_mfma_f32_16x16x32_bf16(
            *(const bf16x8*)(aB + ks * 64 + 32), *(const bf16x8*)(bB + ks * 64 + 32), acc1, 0, 0, 0);
    }
    f32x4 s = acc0 + acc1;
    if (khalf == 1) lsum[rowg * 64 + lane] = s;
    __syncthreads();
    if (khalf == 0) {
        s += lsum[rowg * 64 + lane];
        const int m = m0 + rowg * 16 + kg * 4;
        #pragma unroll
        for (int ri = 0; ri < 4; ++ri)
            lowbf[(size_t)(m + ri) * KEXT + r16] = (bf16_t)s[ri];
    }
    if (tid < 192) {
        bf16x8 z;
        #pragma unroll
        for (int i = 0; i < 8; ++i) z[i] = (bf16_t)0.0f;
        const int row = m0 + tid / 6;
        const int c0  = 16 + (tid % 6) * 8;
        *(bf16x8*)(lowbf + (size_t)row * KEXT + c0) = z;
    }
}

// ---------------------------------------------------------------------------
// GEMM helpers
__device__ __forceinline__ void read_a(bf16x8 (&d)[2][4], const char* base,
                                       int rowB, const int (&swz)[2]) {
    #pragma unroll
    for (int kk = 0; kk < 2; ++kk)
        #pragma unroll
        for (int mi = 0; mi < 4; ++mi)
            d[kk][mi] = *(const bf16x8*)(base + rowB + mi * 2048 + swz[kk]);
}
__device__ __forceinline__ void read_b(bf16x8 (&d)[2][2], const char* base,
                                       int rowB, const int (&swz)[2]) {
    #pragma unroll
    for (int kk = 0; kk < 2; ++kk)
        #pragma unroll
        for (int ni = 0; ni < 2; ++ni)
            d[kk][ni] = *(const bf16x8*)(base + rowB + ni * 2048 + swz[kk]);
}
template<int R0, int C0>
__device__ __forceinline__ void mfma_q(f32x4 (&acc)[8][4],
                                       const bf16x8 (&af)[2][4],
                                       const bf16x8 (&bf)[2][2]) {
    #pragma unroll
    for (int kk = 0; kk < 2; ++kk)
        #pragma unroll
        for (int mi = 0; mi < 4; ++mi)
            #pragma unroll
            for (int ni = 0; ni < 2; ++ni)
                acc[R0 + mi][C0 + ni] = __builtin_amdgcn_mfma_f32_16x16x32_bf16(
                    af[kk][mi], bf[kk][ni], acc[R0 + mi][C0 + ni], 0, 0, 0);
}

// ---------------------------------------------------------------------------
// 256x256 8-phase GEMM — r10 base (231 µs / 56% MfmaUtil) with balanced reads
// 4/8/8/4. FRAGMENT->REGION MAP (r11 lesson — B reads span BOTH Bh halves
// across waves; only the A map is half-clean):
//   a0F reads rows wr*128+{0..63}  = Au units {0,2} for every wave
//   a1F reads rows wr*128+{64..127}= Au units {1,3}
//   b0F/b1F read rows wc*64+{0..63} -> Bh half (wc>>1): SPANS BOTH HALVES
// Therefore: a0F'(t+1) may be read at ph3 behind vmcnt(8) (drains exactly
// Au(t+1,{0,2}) [5ph old] + Bh(t+1,0)x2 [4ph old] — age rule OK), but B0N
// must stay at ph4 behind vmcnt(6) (full tile-t+1 residency).
// Tail: T=63 -> ph3 vmcnt(4), ph4 vmcnt(0). Reads stay INSIDE setprio
// (r7 bistability trigger). Stage ledger identical to r8/r10.
__global__ __launch_bounds__(512, 1) void gemm_lora_kernel(
    const bf16_t* __restrict__ Xbf, const bf16_t* __restrict__ Wbf,
    const bf16_t* __restrict__ lowbf, const bf16_t* __restrict__ lBt,
    const float* __restrict__ bias, float* __restrict__ out)
{
    __shared__ __align__(16) char lds[131072];

    int wg = blockIdx.x;
    const int cpx = gridDim.x >> 3;
    wg = (wg & 7) * cpx + (wg >> 3);

    const int nbn  = N_COLS / BN;            // 16
    const int brow = (wg / nbn) * BM;
    const int bcol = (wg % nbn) * BN;
    const int batch = brow >> 11;

    const int tid  = threadIdx.x;
    const int lane = tid & 63;
    const int w    = tid >> 6;
    const int wr   = w >> 2;
    const int wc   = w & 3;

    const int srow   = tid >> 3;
    const int bphys  = (tid & 7) * 16;
    const int colOff = (bphys ^ ((srow & 7) << 4)) >> 1;

    const bf16_t* aSrc = Xbf + (size_t)(brow + srow) * K_DIM + colOff;
    const bf16_t* bSrc = Wbf + (size_t)(bcol + srow) * K_DIM + colOff;
    const bf16_t* aExt = lowbf + (size_t)(brow + srow) * KEXT + colOff;
    const bf16_t* bExt = lBt + ((size_t)batch * N_COLS + bcol + srow) * KEXT + colOff;

    auto stageAu = [&](int tau, int u) {
        char* dst = lds + (tau & 1) * 65536 + u * 8192 + tid * 16;
        if (tau < NT - 1) gload16(aSrc + (size_t)(u * 64) * K_DIM + tau * BK, dst);
        else              gload16(aExt + (size_t)(u * 64) * KEXT, dst);
    };
    auto stageBh = [&](int tau, int h) {
        char* dst = lds + (tau & 1) * 65536 + 32768 + h * 16384 + tid * 16;
        if (tau < NT - 1) {
            const bf16_t* s = bSrc + (size_t)(h * 128) * K_DIM + tau * BK;
            gload16(s, dst);
            gload16(s + (size_t)64 * K_DIM, dst + 8192);
        } else {
            const bf16_t* s = bExt + (size_t)(h * 128) * KEXT;
            gload16(s, dst);
            gload16(s + 64 * KEXT, dst + 8192);
        }
    };

    const int aRowB = (wr * 128 + (lane & 15)) * 128;
    const int bRowB = (wc * 64 + (lane & 15)) * 128;
    const int swz[2] = { (((lane >> 4) * 16) ^ ((lane & 7) << 4)),
                         ((64 + (lane >> 4) * 16) ^ ((lane & 7) << 4)) };

    f32x4 acc[8][4];
    #pragma unroll
    for (int i = 0; i < 8; ++i)
        #pragma unroll
        for (int j = 0; j < 4; ++j)
            acc[i][j] = (f32x4)0.0f;

    bf16x8 a0F[2][4], a1F[2][4], b1F[2][2], b0Fa[2][2], b0Fb[2][2];

    stageAu(0, 0); stageAu(0, 1); stageAu(0, 2); stageAu(0, 3);
    stageBh(0, 0); stageBh(0, 1);
    stageAu(1, 0); stageAu(1, 2); stageBh(1, 0); stageAu(1, 1); stageAu(1, 3);
    asm volatile("s_waitcnt vmcnt(6)" ::: "memory");
    __builtin_amdgcn_s_barrier();
    read_a(a0F, lds, aRowB, swz);
    read_b(b0Fa, lds + 32768, bRowB, swz);

#define ITER(T, CUR, NXT, B0C, B0N) do {                                      \
    const char* AbC = lds + (CUR) * 65536;                                    \
    const char* BbC = AbC + 32768;                                            \
    const char* AbN = lds + (NXT) * 65536;                                    \
    const char* BbN = AbN + 32768;                                            \
    /* ph1: MFMA q(0,0); issue b1F */                                         \
    if ((T) + 1 <= 64) stageBh((T) + 1, 1);                                   \
    __builtin_amdgcn_s_barrier();                                             \
    asm volatile("s_waitcnt lgkmcnt(0)" ::: "memory");                        \
    __builtin_amdgcn_s_setprio(1);                                            \
    read_b(b1F, BbC + 4096, bRowB, swz);                                      \
    mfma_q<0, 0>(acc, a0F, B0C);                                              \
    __builtin_amdgcn_s_setprio(0);                                            \
    /* ph2: MFMA q(0,1); issue a1F */                                         \
    if ((T) + 2 <= 64) { stageAu((T) + 2, 0); stageAu((T) + 2, 2); }          \
    __builtin_amdgcn_s_barrier();                                             \
    asm volatile("s_waitcnt lgkmcnt(0)" ::: "memory");                        \
    __builtin_amdgcn_s_setprio(1);                                            \
    read_a(a1F, AbC + 8192, aRowB, swz);                                      \
    mfma_q<0, 2>(acc, a0F, b1F);                                              \
    __builtin_amdgcn_s_setprio(0);                                            \
    /* ph3: vmcnt(8) gate drains Au(T+1,{0,2})[5ph]+Bh(T+1,0)[4ph];           \
       a0F' reads ONLY Au units {0,2} (verified map) -> legal here */         \
    if ((T) + 2 <= 64) stageBh((T) + 2, 0);                                   \
    if ((T) < 63) { asm volatile("s_waitcnt vmcnt(8)" ::: "memory"); }        \
    else          { asm volatile("s_waitcnt vmcnt(4)" ::: "memory"); }        \
    __builtin_amdgcn_s_barrier();                                             \
    asm volatile("s_waitcnt lgkmcnt(0)" ::: "memory");                        \
    __builtin_amdgcn_s_setprio(1);                                            \
    if ((T) < 64) read_a(a0F, AbN, aRowB, swz);                               \
    mfma_q<4, 2>(acc, a1F, b1F);                                              \
    __builtin_amdgcn_s_setprio(0);                                            \
    /* ph4: vmcnt(6) gate -> tile T+1 FULLY resident; B0N (spans both Bh      \
       halves across waves) must be read here, not earlier */                 \
    if ((T) + 2 <= 64) { stageAu((T) + 2, 1); stageAu((T) + 2, 3); }          \
    if ((T) < 63) { asm volatile("s_waitcnt vmcnt(6)" ::: "memory"); }        \
    else          { asm volatile("s_waitcnt vmcnt(0)" ::: "memory"); }        \
    __builtin_amdgcn_s_barrier();                                             \
    __builtin_amdgcn_s_setprio(1);                                            \
    if ((T) < 64) read_b(B0N, BbN, bRowB, swz);                               \
    mfma_q<4, 0>(acc, a1F, B0C);                                              \
    __builtin_amdgcn_s_setprio(0);                                            \
} while (0)

    #pragma unroll 1
    for (int t = 0; t < 64; t += 2) {
        ITER(t,     0, 1, b0Fa, b0Fb);
        ITER(t + 1, 1, 0, b0Fb, b0Fa);
    }
    ITER(64, 0, 1, b0Fa, b0Fb);
#undef ITER

    const int cl = lane & 15;
    const int r0 = (lane >> 4) * 4;
    float bv[4];
    #pragma unroll
    for (int nh = 0; nh < 2; ++nh)
        #pragma unroll
        for (int ni = 0; ni < 2; ++ni)
            bv[nh * 2 + ni] = bias[bcol + wc * 64 + nh * 32 + ni * 16 + cl];
    #pragma unroll
    for (int mh = 0; mh < 2; ++mh)
        #pragma unroll
        for (int mi = 0; mi < 4; ++mi) {
            const int row = brow + wr * 128 + mh * 64 + mi * 16 + r0;
            #pragma unroll
            for (int nh = 0; nh < 2; ++nh)
                #pragma unroll
                for (int ni = 0; ni < 2; ++ni) {
                    const int col = bcol + wc * 64 + nh * 32 + ni * 16 + cl;
                    float* op = out + (size_t)row * N_COLS + col;
                    const f32x4 v = acc[mh * 4 + mi][nh * 2 + ni];
                    const float bb = bv[nh * 2 + ni];
                    #pragma unroll
                    for (int r = 0; r < 4; ++r)
                        op[(size_t)r * N_COLS] = v[r] + bb;
                }
        }
}

// ---------------------------------------------------------------------------
extern "C" void kernel_launch(void* const* d_in, const int* in_sizes, int n_in,
                              void* d_out, int out_size, void* d_ws, size_t ws_size,
                              hipStream_t stream) {
    const float* x      = (const float*)d_in[0];
    const float* weight = (const float*)d_in[1];
    const float* bias   = (const float*)d_in[2];
    const float* lora_A = (const float*)d_in[3];
    const float* lora_B = (const float*)d_in[4];
    float* out = (float*)d_out;

    if (ws_size < XBF_BYTES + WBF_BYTES + LOW_BYTES + LBT_BYTES + LAT_BYTES) return;

    char* ws = (char*)d_ws;
    bf16_t* Xbf  = (bf16_t*)ws;
    bf16_t* Wbf  = (bf16_t*)(ws + XBF_BYTES);
    bf16_t* lowb = (bf16_t*)(ws + XBF_BYTES + WBF_BYTES);
    bf16_t* lBt  = (bf16_t*)(ws + XBF_BYTES + WBF_BYTES + LOW_BYTES);
    bf16_t* lAT  = (bf16_t*)(ws + XBF_BYTES + WBF_BYTES + LOW_BYTES + LBT_BYTES);

    prep_kernel<<<1664, 256, 0, stream>>>(x, lora_A, lora_B, weight,
                                          Xbf, Wbf, lBt, lAT);
    lowg_kernel<<<256, 256, 0, stream>>>(Xbf, lAT, lowb);
    gemm_lora_kernel<<<512, 512, 0, stream>>>(Xbf, Wbf, lowb, lBt, bias, out);
}

// Round 13
// 288.761 us; speedup vs baseline: 1.6135x; 1.6135x over previous
//
#include <hip/hip_runtime.h>
#include <hip/hip_bf16.h>
#include <stdint.h>

typedef __bf16 bf16_t;
typedef __bf16 bf16x8 __attribute__((ext_vector_type(8)));
typedef float f32x4 __attribute__((ext_vector_type(4)));

#define M_ROWS 8192
#define N_COLS 4096
#define K_DIM  4096
#define KEXT   64
#define BM 256
#define BN 256
#define BK 64
#define NT 65   // 64 main K-tiles + 1 LoRA extension tile

// ws layout
#define XBF_BYTES (67108864ull)   // 8192*4096*2
#define WBF_BYTES (33554432ull)   // 4096*4096*2
#define LOW_BYTES (1048576ull)    // 8192*64*2
#define LBT_BYTES (2097152ull)    // 4*4096*64*2
#define LAT_BYTES (524288ull)     // 4*16*4096*2

__device__ __forceinline__ void gload16(const void* g, void* l) {
    __builtin_amdgcn_global_load_lds(
        (const __attribute__((address_space(1))) unsigned int*)g,
        (__attribute__((address_space(3))) unsigned int*)l, 16, 0, 0);
}

// ---------------------------------------------------------------------------
// Streaming prep (all coalesced):
//   [0..511]     Xbf = bf16(x)
//   [512..1535]  Wbf = bf16(weight)
//   [1536..1599] lBt[b][n][r] = 2*lora_B[b][r][n] (+zero pad r=16..63)
//   [1600..1663] lAT[b][c][k] = bf16(lora_A[b][k][c])
__global__ __launch_bounds__(256) void prep_kernel(
    const float* __restrict__ x, const float* __restrict__ lA,
    const float* __restrict__ lB, const float* __restrict__ weight,
    bf16_t* __restrict__ Xbf, bf16_t* __restrict__ Wbf,
    bf16_t* __restrict__ lBt, bf16_t* __restrict__ lAT)
{
    const int blk = blockIdx.x;
    const int tid = threadIdx.x;

    if (blk < 512) {
        const long long i0 = (long long)blk * 256 + tid;
        #pragma unroll 1
        for (int it = 0; it < 32; ++it) {
            const long long i = i0 + (long long)it * 131072;
            const f32x4* s = (const f32x4*)(x + i * 8);
            const f32x4 a = s[0], b = s[1];
            bf16x8 v;
            v[0]=(bf16_t)a[0]; v[1]=(bf16_t)a[1]; v[2]=(bf16_t)a[2]; v[3]=(bf16_t)a[3];
            v[4]=(bf16_t)b[0]; v[5]=(bf16_t)b[1]; v[6]=(bf16_t)b[2]; v[7]=(bf16_t)b[3];
            *(bf16x8*)(Xbf + i * 8) = v;
        }
    } else if (blk < 1536) {
        const long long i0 = (long long)(blk - 512) * 256 + tid;
        #pragma unroll 1
        for (int it = 0; it < 8; ++it) {
            const long long i = i0 + (long long)it * 262144;
            const f32x4* s = (const f32x4*)(weight + i * 8);
            const f32x4 a = s[0], b = s[1];
            bf16x8 v;
            v[0]=(bf16_t)a[0]; v[1]=(bf16_t)a[1]; v[2]=(bf16_t)a[2]; v[3]=(bf16_t)a[3];
            v[4]=(bf16_t)b[0]; v[5]=(bf16_t)b[1]; v[6]=(bf16_t)b[2]; v[7]=(bf16_t)b[3];
            *(bf16x8*)(Wbf + i * 8) = v;
        }
    } else if (blk < 1600) {
        const int idx = (blk - 1536) * 256 + tid;   // 0..16383
        const int b = idx >> 12, n = idx & 4095;
        const float* src = lB + (size_t)b * (16 * N_COLS) + n;
        bf16_t* dst = lBt + ((size_t)b * N_COLS + n) * KEXT;
        bf16x8 v0, v1, z;
        #pragma unroll
        for (int r = 0; r < 8; ++r) {
            v0[r] = (bf16_t)(2.0f * src[(size_t)r * N_COLS]);
            v1[r] = (bf16_t)(2.0f * src[(size_t)(8 + r) * N_COLS]);
            z[r]  = (bf16_t)0.0f;
        }
        *(bf16x8*)(dst)     = v0;
        *(bf16x8*)(dst + 8) = v1;
        #pragma unroll
        for (int c = 16; c < 64; c += 8)
            *(bf16x8*)(dst + c) = z;
    } else {
        const int q = blk - 1600;              // 0..63
        const int b = q >> 4, c = q & 15;
        const float* src = lA + (size_t)b * (K_DIM * 16) + c;
        bf16_t* dst = lAT + ((size_t)b * 16 + c) * K_DIM + tid * 16;
        bf16x8 v0, v1;
        #pragma unroll
        for (int j = 0; j < 8; ++j) {
            v0[j] = (bf16_t)src[(size_t)(tid * 16 + j) * 16];
            v1[j] = (bf16_t)src[(size_t)(tid * 16 + 8 + j) * 16];
        }
        *(bf16x8*)(dst)     = v0;
        *(bf16x8*)(dst + 8) = v1;
    }
}

// ---------------------------------------------------------------------------
// low = Xbf @ lora_A via MFMA. 256 blocks x 32 rows; 4 waves =
// (rowg 0..1 -> 16 rows) x (khalf 0..1 -> K half). 2 interleaved acc chains.
__global__ __launch_bounds__(256) void lowg_kernel(
    const bf16_t* __restrict__ Xbf, const bf16_t* __restrict__ lAT,
    bf16_t* __restrict__ lowbf)
{
    __shared__ f32x4 lsum[128];
    const int tid  = threadIdx.x;
    const int w    = tid >> 6;
    const int lane = tid & 63;
    const int rowg = w >> 1, khalf = w & 1;
    const int m0   = blockIdx.x * 32;
    const int batch = m0 >> 11;
    const int r16  = lane & 15;
    const int kg   = lane >> 4;

    const bf16_t* aB = Xbf + (size_t)(m0 + rowg * 16 + r16) * K_DIM + khalf * 2048 + kg * 8;
    const bf16_t* bB = lAT + ((size_t)batch * 16 + r16) * K_DIM + khalf * 2048 + kg * 8;

    f32x4 acc0 = (f32x4)0.0f, acc1 = (f32x4)0.0f;
    #pragma unroll 4
    for (int ks = 0; ks < 32; ++ks) {
        acc0 = __builtin_amdgcn_mfma_f32_16x16x32_bf16(
            *(const bf16x8*)(aB + ks * 64), *(const bf16x8*)(bB + ks * 64), acc0, 0, 0, 0);
        acc1 = __builtin_amdgcn_mfma_f32_16x16x32_bf16(
            *(const bf16x8*)(aB + ks * 64 + 32), *(const bf16x8*)(bB + ks * 64 + 32), acc1, 0, 0, 0);
    }
    f32x4 s = acc0 + acc1;
    if (khalf == 1) lsum[rowg * 64 + lane] = s;
    __syncthreads();
    if (khalf == 0) {
        s += lsum[rowg * 64 + lane];
        const int m = m0 + rowg * 16 + kg * 4;
        #pragma unroll
        for (int ri = 0; ri < 4; ++ri)
            lowbf[(size_t)(m + ri) * KEXT + r16] = (bf16_t)s[ri];
    }
    if (tid < 192) {
        bf16x8 z;
        #pragma unroll
        for (int i = 0; i < 8; ++i) z[i] = (bf16_t)0.0f;
        const int row = m0 + tid / 6;
        const int c0  = 16 + (tid % 6) * 8;
        *(bf16x8*)(lowbf + (size_t)row * KEXT + c0) = z;
    }
}

// ---------------------------------------------------------------------------
// GEMM helpers
__device__ __forceinline__ void read_a(bf16x8 (&d)[2][4], const char* base,
                                       int rowB, const int (&swz)[2]) {
    #pragma unroll
    for (int kk = 0; kk < 2; ++kk)
        #pragma unroll
        for (int mi = 0; mi < 4; ++mi)
            d[kk][mi] = *(const bf16x8*)(base + rowB + mi * 2048 + swz[kk]);
}
__device__ __forceinline__ void read_b(bf16x8 (&d)[2][2], const char* base,
                                       int rowB, const int (&swz)[2]) {
    #pragma unroll
    for (int kk = 0; kk < 2; ++kk)
        #pragma unroll
        for (int ni = 0; ni < 2; ++ni)
            d[kk][ni] = *(const bf16x8*)(base + rowB + ni * 2048 + swz[kk]);
}
template<int R0, int C0>
__device__ __forceinline__ void mfma_q(f32x4 (&acc)[8][4],
                                       const bf16x8 (&af)[2][4],
                                       const bf16x8 (&bf)[2][2]) {
    #pragma unroll
    for (int kk = 0; kk < 2; ++kk)
        #pragma unroll
        for (int mi = 0; mi < 4; ++mi)
            #pragma unroll
            for (int ni = 0; ni < 2; ++ni)
                acc[R0 + mi][C0 + ni] = __builtin_amdgcn_mfma_f32_16x16x32_bf16(
                    af[kk][mi], bf[kk][ni], acc[R0 + mi][C0 + ni], 0, 0, 0);
}

// ---------------------------------------------------------------------------
// 256x256 8-phase GEMM — r10 FINAL (proven 231 µs / 56% MfmaUtil / FETCH
// 300 MB). 4 barriers/iter, SINGLE vmcnt(6) gate at ph4, all frag reads
// inside setprio(1), read-ahead one phase (ph1:b1F, ph2:a1F, ph4:a0F'+B0').
// DO NOT add a second vmcnt gate per iter (r6 vmcnt(10), r12 vmcnt(8) both
// -> slow state): a second gate caps in-flight loads at 12 (vs 14 here),
// and the lost elasticity under HBM-latency jitter desyncs blocks, collapses
// cross-block L2 reuse (FETCH 300->535 MB), and self-sustains (~2x slower).
// Deeper prefetch to restore headroom needs 3-deep LDS dbuf = 192 KB > 160.
// DO NOT move reads out of setprio (r5/-14%, r7/-47%, r9/-9% variants).
__global__ __launch_bounds__(512, 1) void gemm_lora_kernel(
    const bf16_t* __restrict__ Xbf, const bf16_t* __restrict__ Wbf,
    const bf16_t* __restrict__ lowbf, const bf16_t* __restrict__ lBt,
    const float* __restrict__ bias, float* __restrict__ out)
{
    __shared__ __align__(16) char lds[131072];

    int wg = blockIdx.x;
    const int cpx = gridDim.x >> 3;
    wg = (wg & 7) * cpx + (wg >> 3);

    const int nbn  = N_COLS / BN;            // 16
    const int brow = (wg / nbn) * BM;
    const int bcol = (wg % nbn) * BN;
    const int batch = brow >> 11;

    const int tid  = threadIdx.x;
    const int lane = tid & 63;
    const int w    = tid >> 6;
    const int wr   = w >> 2;
    const int wc   = w & 3;

    const int srow   = tid >> 3;
    const int bphys  = (tid & 7) * 16;
    const int colOff = (bphys ^ ((srow & 7) << 4)) >> 1;

    const bf16_t* aSrc = Xbf + (size_t)(brow + srow) * K_DIM + colOff;
    const bf16_t* bSrc = Wbf + (size_t)(bcol + srow) * K_DIM + colOff;
    const bf16_t* aExt = lowbf + (size_t)(brow + srow) * KEXT + colOff;
    const bf16_t* bExt = lBt + ((size_t)batch * N_COLS + bcol + srow) * KEXT + colOff;

    auto stageAu = [&](int tau, int u) {
        char* dst = lds + (tau & 1) * 65536 + u * 8192 + tid * 16;
        if (tau < NT - 1) gload16(aSrc + (size_t)(u * 64) * K_DIM + tau * BK, dst);
        else              gload16(aExt + (size_t)(u * 64) * KEXT, dst);
    };
    auto stageBh = [&](int tau, int h) {
        char* dst = lds + (tau & 1) * 65536 + 32768 + h * 16384 + tid * 16;
        if (tau < NT - 1) {
            const bf16_t* s = bSrc + (size_t)(h * 128) * K_DIM + tau * BK;
            gload16(s, dst);
            gload16(s + (size_t)64 * K_DIM, dst + 8192);
        } else {
            const bf16_t* s = bExt + (size_t)(h * 128) * KEXT;
            gload16(s, dst);
            gload16(s + 64 * KEXT, dst + 8192);
        }
    };

    const int aRowB = (wr * 128 + (lane & 15)) * 128;
    const int bRowB = (wc * 64 + (lane & 15)) * 128;
    const int swz[2] = { (((lane >> 4) * 16) ^ ((lane & 7) << 4)),
                         ((64 + (lane >> 4) * 16) ^ ((lane & 7) << 4)) };

    f32x4 acc[8][4];
    #pragma unroll
    for (int i = 0; i < 8; ++i)
        #pragma unroll
        for (int j = 0; j < 4; ++j)
            acc[i][j] = (f32x4)0.0f;

    bf16x8 a0F[2][4], a1F[2][4], b1F[2][2], b0Fa[2][2], b0Fb[2][2];

    stageAu(0, 0); stageAu(0, 1); stageAu(0, 2); stageAu(0, 3);
    stageBh(0, 0); stageBh(0, 1);
    stageAu(1, 0); stageAu(1, 2); stageBh(1, 0); stageAu(1, 1); stageAu(1, 3);
    asm volatile("s_waitcnt vmcnt(6)" ::: "memory");
    __builtin_amdgcn_s_barrier();
    read_a(a0F, lds, aRowB, swz);
    read_b(b0Fa, lds + 32768, bRowB, swz);

#define ITER(T, CUR, NXT, B0C, B0N) do {                                      \
    const char* AbC = lds + (CUR) * 65536;                                    \
    const char* BbC = AbC + 32768;                                            \
    const char* AbN = lds + (NXT) * 65536;                                    \
    const char* BbN = AbN + 32768;                                            \
    /* ph1: MFMA q(0,0); issue b1F */                                         \
    if ((T) + 1 <= 64) stageBh((T) + 1, 1);                                   \
    __builtin_amdgcn_s_barrier();                                             \
    asm volatile("s_waitcnt lgkmcnt(0)" ::: "memory");                        \
    __builtin_amdgcn_s_setprio(1);                                            \
    read_b(b1F, BbC + 4096, bRowB, swz);                                      \
    mfma_q<0, 0>(acc, a0F, B0C);                                              \
    __builtin_amdgcn_s_setprio(0);                                            \
    /* ph2: MFMA q(0,1); issue a1F */                                         \
    if ((T) + 2 <= 64) { stageAu((T) + 2, 0); stageAu((T) + 2, 2); }          \
    __builtin_amdgcn_s_barrier();                                             \
    asm volatile("s_waitcnt lgkmcnt(0)" ::: "memory");                        \
    __builtin_amdgcn_s_setprio(1);                                            \
    read_a(a1F, AbC + 8192, aRowB, swz);                                      \
    mfma_q<0, 2>(acc, a0F, b1F);                                              \
    __builtin_amdgcn_s_setprio(0);                                            \
    /* ph3: MFMA q(1,1) */                                                    \
    if ((T) + 2 <= 64) stageBh((T) + 2, 0);                                   \
    __builtin_amdgcn_s_barrier();                                             \
    asm volatile("s_waitcnt lgkmcnt(0)" ::: "memory");                        \
    __builtin_amdgcn_s_setprio(1);                                            \
    mfma_q<4, 2>(acc, a1F, b1F);                                              \
    __builtin_amdgcn_s_setprio(0);                                            \
    /* ph4: vmcnt gate -> tile T+1 resident; reads INSIDE setprio */          \
    if ((T) + 2 <= 64) { stageAu((T) + 2, 1); stageAu((T) + 2, 3); }          \
    if ((T) < 63) { asm volatile("s_waitcnt vmcnt(6)" ::: "memory"); }        \
    else          { asm volatile("s_waitcnt vmcnt(0)" ::: "memory"); }        \
    __builtin_amdgcn_s_barrier();                                             \
    __builtin_amdgcn_s_setprio(1);                                            \
    if ((T) < 64) { read_a(a0F, AbN, aRowB, swz);                             \
                    read_b(B0N, BbN, bRowB, swz); }                           \
    mfma_q<4, 0>(acc, a1F, B0C);                                              \
    __builtin_amdgcn_s_setprio(0);                                            \
} while (0)

    #pragma unroll 1
    for (int t = 0; t < 64; t += 2) {
        ITER(t,     0, 1, b0Fa, b0Fb);
        ITER(t + 1, 1, 0, b0Fb, b0Fa);
    }
    ITER(64, 0, 1, b0Fa, b0Fb);
#undef ITER

    const int cl = lane & 15;
    const int r0 = (lane >> 4) * 4;
    float bv[4];
    #pragma unroll
    for (int nh = 0; nh < 2; ++nh)
        #pragma unroll
        for (int ni = 0; ni < 2; ++ni)
            bv[nh * 2 + ni] = bias[bcol + wc * 64 + nh * 32 + ni * 16 + cl];
    #pragma unroll
    for (int mh = 0; mh < 2; ++mh)
        #pragma unroll
        for (int mi = 0; mi < 4; ++mi) {
            const int row = brow + wr * 128 + mh * 64 + mi * 16 + r0;
            #pragma unroll
            for (int nh = 0; nh < 2; ++nh)
                #pragma unroll
                for (int ni = 0; ni < 2; ++ni) {
                    const int col = bcol + wc * 64 + nh * 32 + ni * 16 + cl;
                    float* op = out + (size_t)row * N_COLS + col;
                    const f32x4 v = acc[mh * 4 + mi][nh * 2 + ni];
                    const float bb = bv[nh * 2 + ni];
                    #pragma unroll
                    for (int r = 0; r < 4; ++r)
                        op[(size_t)r * N_COLS] = v[r] + bb;
                }
        }
}

// ---------------------------------------------------------------------------
extern "C" void kernel_launch(void* const* d_in, const int* in_sizes, int n_in,
                              void* d_out, int out_size, void* d_ws, size_t ws_size,
                              hipStream_t stream) {
    const float* x      = (const float*)d_in[0];
    const float* weight = (const float*)d_in[1];
    const float* bias   = (const float*)d_in[2];
    const float* lora_A = (const float*)d_in[3];
    const float* lora_B = (const float*)d_in[4];
    float* out = (float*)d_out;

    if (ws_size < XBF_BYTES + WBF_BYTES + LOW_BYTES + LBT_BYTES + LAT_BYTES) return;

    char* ws = (char*)d_ws;
    bf16_t* Xbf  = (bf16_t*)ws;
    bf16_t* Wbf  = (bf16_t*)(ws + XBF_BYTES);
    bf16_t* lowb = (bf16_t*)(ws + XBF_BYTES + WBF_BYTES);
    bf16_t* lBt  = (bf16_t*)(ws + XBF_BYTES + WBF_BYTES + LOW_BYTES);
    bf16_t* lAT  = (bf16_t*)(ws + XBF_BYTES + WBF_BYTES + LOW_BYTES + LBT_BYTES);

    prep_kernel<<<1664, 256, 0, stream>>>(x, lora_A, lora_B, weight,
                                          Xbf, Wbf, lBt, lAT);
    lowg_kernel<<<256, 256, 0, stream>>>(Xbf, lAT, lowb);
    gemm_lora_kernel<<<512, 512, 0, stream>>>(Xbf, Wbf, lowb, lBt, bias, out);
}